// Round 11
// baseline (143.553 us; speedup 1.0000x reference)
//
#include <hip/hip_runtime.h>
#include <math.h>

#define NCAM 6
#define C_CH 64
#define HF   64
#define WF   176
#define GDIM 129
#define NY   4
#define NH   3
#define DD   128
#define WDIM 128
#define NP   (DD*WDIM)

#define ROWB (WF*C_CH*4)          // integral row stride, bytes (45056)
#define COLB (C_CH*4)             // integral col stride, bytes (256)
#define IMGB ((size_t)HF*WF*C_CH*4)

// Packed box params, 32B = 8 dwords, laid out [vox][cam] (one voxel's 6 cams
// contiguous = 192B). dword0 = yT0|yB0<<8|xL0<<16|xR0<<24; 1..4 = wxL,wxR,wyT,wyB;
// 5 = area. No clamps on +1 offsets: boundary lerp weights are exactly 0 and integ
// is padded, so overread rows/cols are finite-garbage × 0.

__device__ __forceinline__ float bcf(int x) {
    return __builtin_bit_cast(float, x);
}

// ---------------- Kernel 1: FUSED row-cumsum (384 blocks) || boxproj (1152 blocks) ----
__global__ __launch_bounds__(256) void k_prep(const float* __restrict__ feat,
                                              float* __restrict__ integ,
                                              const float* __restrict__ ks,
                                              const float* __restrict__ imu2cs,
                                              const float* __restrict__ post_rots,
                                              const float* __restrict__ post_trans,
                                              const float* __restrict__ undists,
                                              const float* __restrict__ grid,
                                              int4* __restrict__ bp)
{
    __shared__ float T[WF * 65];
    __shared__ float S[4][C_CH];
    __shared__ float OFF[4][C_CH];
    const int bx  = blockIdx.x;
    const int tid = threadIdx.x;

    if (bx < HF * NCAM) {
        // ---- row cumsum (axis=-1) -> channel-last, into integ ----
        const int n = bx / HF;
        const int h = bx % HF;

        for (int idx = tid; idx < C_CH * WF; idx += 256) {
            const int cc = idx / WF;
            const int w  = idx % WF;
            T[w*65 + cc] = feat[((size_t)(n*C_CH + cc)*HF + h)*WF + w];
        }
        __syncthreads();
        {
            const int cc = tid & 63, seg = tid >> 6;
            const int w0 = seg * 44;
            float run = 0.0f;
            #pragma unroll
            for (int i = 0; i < 44; ++i) {
                run += T[(w0 + i)*65 + cc];
                T[(w0 + i)*65 + cc] = run;
            }
            S[seg][cc] = run;
        }
        __syncthreads();
        {
            const int cc = tid & 63, seg = tid >> 6;
            float off = 0.0f;
            #pragma unroll
            for (int s = 0; s < 3; ++s)
                if (s < seg) off += S[s][cc];
            OFF[seg][cc] = off;
        }
        __syncthreads();
        float* outp = integ + (size_t)(n*HF + h) * (WF * C_CH);
        for (int idx = tid; idx < WF * C_CH; idx += 256) {
            const int w  = idx >> 6;
            const int cc = idx & 63;
            outp[idx] = T[w*65 + cc] + OFF[w/44][cc];
        }
        return;
    }

    // ---- boxproj: project 8 voxel corners + bbox -> packed params ----
    const int idx = (bx - HF*NCAM) * 256 + tid;
    if (idx >= NCAM * NH * NP) return;
    const int vox = idx / NCAM;
    const int n   = idx - vox * NCAM;     // cam fastest -> coalesced 32B writes
    const int nh  = vox / NP;
    const int p   = vox - nh * NP;
    const int d   = p / WDIM;
    const int wd  = p - d * WDIM;

    const float* k  = ks         + n * 9;
    const float* m  = imu2cs     + n * 12;
    const float* pr = post_rots  + n * 9;
    const float* pt = post_trans + n * 3;
    const float* D  = undists    + n * 7;

    float cal[12];
    #pragma unroll
    for (int i = 0; i < 3; ++i)
        #pragma unroll
        for (int j = 0; j < 4; ++j)
            cal[i*4+j] = k[i*3+0]*m[0*4+j] + k[i*3+1]*m[1*4+j] + k[i*3+2]*m[2*4+j];

    const float fx = k[0], fy = k[4], cx = k[2], cy = k[5];
    const float rfx = 1.0f / fx, rfy = 1.0f / fy;
    const bool fish = (D[6] == 1.0f);
    const float D0 = D[0], D1 = D[1], D2 = D[2], D3 = D[3], D4 = D[4], D5 = D[5];

    float left = 1e30f, right = -1e30f, top = 1e30f, bot = -1e30f;
    #pragma unroll
    for (int a = 0; a < 2; ++a) {
        const float vy = 2.0f - (float)(nh + a);   // ys = -arange(0,4)+2
        #pragma unroll
        for (int b = 0; b < 2; ++b) {
            #pragma unroll
            for (int cc = 0; cc < 2; ++cc) {
                const int gz = d + b, gx = wd + cc;
                const float vx = grid[(gz*GDIM + gx)*3 + 0];
                const float vz = grid[(gz*GDIM + gx)*3 + 2];

                const float hx = cal[0]*vx + cal[1]*vy + cal[2]*vz  + cal[3];
                const float hy = cal[4]*vx + cal[5]*vy + cal[6]*vz  + cal[7];
                const float hz = cal[8]*vx + cal[9]*vy + cal[10]*vz + cal[11];

                const float fl = (hz > 0.0f) ? 1.0f : 0.0f;
                const float px = (hx * fl) / hz;
                const float py = (hy * fl) / hz;

                const float x = (px - cx) * rfx;
                const float y = (py - cy) * rfy;

                float xd, yd;
                if (fish) {
                    const float rr = sqrtf(x*x + y*y);
                    const float th = atanf(rr);
                    const float t2 = th * th;
                    const float t4 = t2 * t2;
                    const float rad = th * (1.0f + D0*t2 + D1*t4 + D2*(t2*t4) + D5*(t4*t4)) / rr;
                    xd = x * rad * fx + cx;
                    yd = y * rad * fy + cy;
                } else {
                    const float r2 = x*x + y*y;
                    const float poly = 1.0f + D0*r2 + D1*r2*r2 + D2*r2*r2*r2;
                    const float xdd = x*poly + (2.0f*D3*x*y + D4*(r2 + 2.0f*x*x));
                    const float ydd = y*poly + (D3*(r2 + 2.0f*y*y) + 2.0f*D4*x*y);
                    xd = xdd * fx + cx;
                    yd = ydd * fy + cy;
                }
                xd *= fl; yd *= fl;

                const float qx = pr[0]*xd + pr[1]*yd + pt[0];
                const float qy = pr[3]*xd + pr[4]*yd + pt[1];
                const float ncx = fminf(fmaxf(2.0f*qx - 1.0f, -1.0f), 1.0f);
                const float ncy = fminf(fmaxf(2.0f*qy - 1.0f, -1.0f), 1.0f);

                left  = fminf(left,  ncx);  right = fmaxf(right, ncx);
                top   = fminf(top,   ncy);  bot   = fmaxf(bot,   ncy);
            }
        }
    }

    const float area = (right - left) * (bot - top) * (float)HF * (float)WF * 0.25f + 1e-6f;

    const float xLp = fminf(fmaxf((left  + 1.0f) * 0.5f * (float)(WF-1), 0.0f), (float)(WF-1));
    const float xRp = fminf(fmaxf((right + 1.0f) * 0.5f * (float)(WF-1), 0.0f), (float)(WF-1));
    const float yTp = fminf(fmaxf((top   + 1.0f) * 0.5f * (float)(HF-1), 0.0f), (float)(HF-1));
    const float yBp = fminf(fmaxf((bot   + 1.0f) * 0.5f * (float)(HF-1), 0.0f), (float)(HF-1));
    const float xL0 = floorf(xLp), xR0 = floorf(xRp), yT0 = floorf(yTp), yB0 = floorf(yBp);

    const int pyx = (int)yT0 | ((int)yB0 << 8) | ((int)xL0 << 16) | ((int)xR0 << 24);

    int4 o0, o1;
    o0.x = pyx;
    o0.y = __builtin_bit_cast(int, xLp - xL0);
    o0.z = __builtin_bit_cast(int, xRp - xR0);
    o0.w = __builtin_bit_cast(int, yTp - yT0);
    o1.x = __builtin_bit_cast(int, yBp - yB0);
    o1.y = __builtin_bit_cast(int, area);
    o1.z = 0; o1.w = 0;
    bp[(size_t)idx*2 + 0] = o0;
    bp[(size_t)idx*2 + 1] = o1;
}

// ---------------- Kernel 2: column cumsum IN PLACE -> integral [n][h][x][c] -----------
__global__ __launch_bounds__(256) void k_colcum(float* __restrict__ integ)
{
    __shared__ float tA[4][C_CH];
    const int x  = blockIdx.x;
    const int n  = blockIdx.y;
    const int c  = threadIdx.x & 63;
    const int hq = threadIdx.x >> 6;

    float* base = integ + (size_t)n*HF*WF*C_CH + (size_t)x * C_CH + c;
    float e[16];
    #pragma unroll
    for (int i = 0; i < 16; ++i)
        e[i] = base[(size_t)(hq*16 + i) * (WF*C_CH)];
    #pragma unroll
    for (int i = 1; i < 16; ++i)
        e[i] += e[i-1];
    tA[hq][c] = e[15];
    __syncthreads();
    float off = 0.0f;
    #pragma unroll
    for (int s = 0; s < 3; ++s)
        if (s < hq) off += tA[s][c];
    #pragma unroll
    for (int i = 0; i < 16; ++i)
        base[(size_t)(hq*16 + i) * (WF*C_CH)] = e[i] + off;
}

// ---------------- Kernel 3: sample integral image, combine, max over cameras ----------
// R7-proven body, retiled: 24 voxels/block -> 2048 blocks = EXACTLY 8 blocks/CU at
// __launch_bounds__(256,8) (VGPR 28 << 64-reg budget) -> 32 waves/CU co-resident,
// 33% more outstanding loads feeding L2. XCD-swizzled contiguous 256-tile bands.
// Wave = 6 voxels; camera-PAIR batching; one-voxel-ahead param prefetch via readlane.
__global__ __launch_bounds__(256, 8) void k_sample(const float* __restrict__ integ,
                                                   const int* __restrict__ bpi,
                                                   float* __restrict__ out)
{
    __shared__ float sm[24][65];
    const int bx   = blockIdx.x;
    const int xcd  = bx & 7;
    const int slot = bx >> 3;
    const int gt   = xcd * 256 + slot;          // contiguous tile band per XCD
    const int v0   = gt * 24;                   // global voxel id base (nh-major)
    const int tid  = threadIdx.x;
    const int wave = __builtin_amdgcn_readfirstlane(tid >> 6);
    const int c    = tid & 63;
    const int pl   = (c < 48) ? c : (c - 48);   // dword index within 192B param block

    const int* bpw = bpi + (size_t)(v0 + wave*6) * 48;

    int vpc = bpw[pl];                           // params for j=0
    #pragma unroll 1
    for (int j = 0; j < 6; ++j) {
        int vpn = vpc;
        if (j < 5) vpn = bpw[(j + 1) * 48 + pl]; // prefetch next voxel's params

        float vmax = -3.402823466e38f;
        #pragma unroll
        for (int pr2 = 0; pr2 < 3; ++pr2) {
            const int camA = pr2*2, camB = pr2*2 + 1;
            const int fA = __builtin_amdgcn_readlane(vpc, camA*8 + 0);
            const float wxlA = bcf(__builtin_amdgcn_readlane(vpc, camA*8 + 1));
            const float wxrA = bcf(__builtin_amdgcn_readlane(vpc, camA*8 + 2));
            const float wytA = bcf(__builtin_amdgcn_readlane(vpc, camA*8 + 3));
            const float wybA = bcf(__builtin_amdgcn_readlane(vpc, camA*8 + 4));
            const float arA  = bcf(__builtin_amdgcn_readlane(vpc, camA*8 + 5));
            const int fB = __builtin_amdgcn_readlane(vpc, camB*8 + 0);
            const float wxlB = bcf(__builtin_amdgcn_readlane(vpc, camB*8 + 1));
            const float wxrB = bcf(__builtin_amdgcn_readlane(vpc, camB*8 + 2));
            const float wytB = bcf(__builtin_amdgcn_readlane(vpc, camB*8 + 3));
            const float wybB = bcf(__builtin_amdgcn_readlane(vpc, camB*8 + 4));
            const float arB  = bcf(__builtin_amdgcn_readlane(vpc, camB*8 + 5));

            float tA[16], tB[16];
            {
                const int yT = fA & 255, yB2 = (fA >> 8) & 255;
                const int xL = (fA >> 16) & 255, xR = (fA >> 24) & 255;
                const int r0 = yT * ROWB, r2 = yB2 * ROWB;
                const int c0 = xL * COLB, c2 = xR * COLB;
                const char* b = (const char*)integ + (size_t)camA * IMGB;
                #pragma unroll
                for (int rr = 0; rr < 4; ++rr) {
                    const int ro = ((rr < 2) ? r0 : r2) + ((rr & 1) ? ROWB : 0);
                    #pragma unroll
                    for (int cc2 = 0; cc2 < 4; ++cc2) {
                        const int co = ((cc2 < 2) ? c0 : c2) + ((cc2 & 1) ? COLB : 0);
                        tA[rr*4 + cc2] = ((const float*)(b + (size_t)(ro + co)))[c];
                    }
                }
            }
            {
                const int yT = fB & 255, yB2 = (fB >> 8) & 255;
                const int xL = (fB >> 16) & 255, xR = (fB >> 24) & 255;
                const int r0 = yT * ROWB, r2 = yB2 * ROWB;
                const int c0 = xL * COLB, c2 = xR * COLB;
                const char* b = (const char*)integ + (size_t)camB * IMGB;
                #pragma unroll
                for (int rr = 0; rr < 4; ++rr) {
                    const int ro = ((rr < 2) ? r0 : r2) + ((rr & 1) ? ROWB : 0);
                    #pragma unroll
                    for (int cc2 = 0; cc2 < 4; ++cc2) {
                        const int co = ((cc2 < 2) ? c0 : c2) + ((cc2 & 1) ? COLB : 0);
                        tB[rr*4 + cc2] = ((const float*)(b + (size_t)(ro + co)))[c];
                    }
                }
            }

            {
                const float A0 = fmaf(wxlA, tA[1]  - tA[0],  tA[0]);
                const float B0 = fmaf(wxrA, tA[3]  - tA[2],  tA[2]);
                const float A1 = fmaf(wxlA, tA[5]  - tA[4],  tA[4]);
                const float B1 = fmaf(wxrA, tA[7]  - tA[6],  tA[6]);
                const float A2 = fmaf(wxlA, tA[9]  - tA[8],  tA[8]);
                const float B2 = fmaf(wxrA, tA[11] - tA[10], tA[10]);
                const float A3 = fmaf(wxlA, tA[13] - tA[12], tA[12]);
                const float B3 = fmaf(wxrA, tA[15] - tA[14], tA[14]);
                const float d0 = A0 - B0, d1 = A1 - B1;
                const float e0 = B2 - A2, e1 = B3 - A3;
                const float s = fmaf(wytA, d1 - d0, d0) + fmaf(wybA, e1 - e0, e0);
                float v = s * __builtin_amdgcn_rcpf(arA);
                v = (arA > 1e-6f) ? v : 0.0f;    // reference: vox * (area > EPS)
                vmax = fmaxf(vmax, v);
            }
            {
                const float A0 = fmaf(wxlB, tB[1]  - tB[0],  tB[0]);
                const float B0 = fmaf(wxrB, tB[3]  - tB[2],  tB[2]);
                const float A1 = fmaf(wxlB, tB[5]  - tB[4],  tB[4]);
                const float B1 = fmaf(wxrB, tB[7]  - tB[6],  tB[6]);
                const float A2 = fmaf(wxlB, tB[9]  - tB[8],  tB[8]);
                const float B2 = fmaf(wxrB, tB[11] - tB[10], tB[10]);
                const float A3 = fmaf(wxlB, tB[13] - tB[12], tB[12]);
                const float B3 = fmaf(wxrB, tB[15] - tB[14], tB[14]);
                const float d0 = A0 - B0, d1 = A1 - B1;
                const float e0 = B2 - A2, e1 = B3 - A3;
                const float s = fmaf(wytB, d1 - d0, d0) + fmaf(wybB, e1 - e0, e0);
                float v = s * __builtin_amdgcn_rcpf(arB);
                v = (arB > 1e-6f) ? v : 0.0f;
                vmax = fmaxf(vmax, v);
            }
        }
        sm[wave*6 + j][c] = vmax;
        vpc = vpn;
    }
    __syncthreads();
    // store 24 voxels x 64 channels
    #pragma unroll
    for (int it = 0; it < 6; ++it) {
        const int idx = it*256 + tid;      // 0..1535
        const int cc  = idx / 24;
        const int jj  = idx - cc*24;
        const int v   = v0 + jj;
        const int nh  = v >> 14;           // / NP
        const int p   = v & (NP - 1);
        out[(size_t)(cc*NH + nh)*NP + p] = sm[jj][cc];
    }
}

extern "C" void kernel_launch(void* const* d_in, const int* in_sizes, int n_in,
                              void* d_out, int out_size, void* d_ws, size_t ws_size,
                              hipStream_t stream)
{
    const float* feats      = (const float*)d_in[0];  // [1,6,64,64,176]
    const float* ks         = (const float*)d_in[1];  // [1,6,3,3]
    const float* imu2cs     = (const float*)d_in[2];  // [1,6,3,4]
    const float* post_rots  = (const float*)d_in[3];  // [1,6,3,3]
    const float* post_trans = (const float*)d_in[4];  // [1,6,3]
    const float* undists    = (const float*)d_in[5];  // [1,6,7]
    const float* grid       = (const float*)d_in[6];  // [1,129,129,3]
    float* out = (float*)d_out;                       // [1,192,128,128]

    char* ws = (char*)d_ws;
    size_t off = 0;
    float* integ = (float*)(ws + off);                // rowsum then integral (in place)
    off += (size_t)NCAM * IMGB + ROWB + 65536;        // pad: clamp-free overreads (x0 wt)
    off = (off + 255) & ~(size_t)255;
    int4* bp = (int4*)(ws + off);
    off += (size_t)NCAM * NH * NP * 32 + 256;
    (void)ws_size; (void)in_sizes; (void)n_in; (void)out_size;

    // K1: fused row-cumsum (384 blocks) || boxproj (1152 blocks)
    dim3 g1(HF*NCAM + (NCAM*NH*NP + 255)/256);
    k_prep<<<g1, 256, 0, stream>>>(feats, integ, ks, imu2cs, post_rots, post_trans,
                                   undists, grid, bp);

    // K2: column cumsum in place
    dim3 g2(WF, NCAM);
    k_colcum<<<g2, 256, 0, stream>>>(integ);

    // K3: sampling, 2048 blocks = 8/CU single round
    dim3 g3(NH*NP/24);
    k_sample<<<g3, 256, 0, stream>>>(integ, (const int*)bp, out);
}

// Round 12
// 143.529 us; speedup vs baseline: 1.0002x; 1.0002x over previous
//
#include <hip/hip_runtime.h>
#include <math.h>

#define NCAM 6
#define C_CH 64
#define HF   64
#define WF   176
#define GDIM 129
#define NY   4
#define NH   3
#define DD   128
#define WDIM 128
#define NP   (DD*WDIM)

#define ROWB (WF*C_CH*4)          // integral row stride, bytes (45056)
#define COLB (C_CH*4)             // integral col stride, bytes (256)
#define IMGB ((size_t)HF*WF*C_CH*4)

// Packed box params, 32B = 8 dwords, laid out [vox][cam] (one voxel's 6 cams
// contiguous = 192B). dword0 = yT0|yB0<<8|xL0<<16|xR0<<24; 1..4 = wxL,wxR,wyT,wyB;
// 5 = area. No clamps on +1 offsets: boundary lerp weights are exactly 0 and integ
// is padded, so overread rows/cols are finite-garbage × 0.

__device__ __forceinline__ float bcf(int x) {
    return __builtin_bit_cast(float, x);
}

// ---------------- Kernel 1: FUSED row-cumsum (384 blocks) || boxproj (1152 blocks) ----
__global__ __launch_bounds__(256) void k_prep(const float* __restrict__ feat,
                                              float* __restrict__ integ,
                                              const float* __restrict__ ks,
                                              const float* __restrict__ imu2cs,
                                              const float* __restrict__ post_rots,
                                              const float* __restrict__ post_trans,
                                              const float* __restrict__ undists,
                                              const float* __restrict__ grid,
                                              int4* __restrict__ bp)
{
    __shared__ float T[WF * 65];
    __shared__ float S[4][C_CH];
    __shared__ float OFF[4][C_CH];
    const int bx  = blockIdx.x;
    const int tid = threadIdx.x;

    if (bx < HF * NCAM) {
        // ---- row cumsum (axis=-1) -> channel-last, into integ ----
        const int n = bx / HF;
        const int h = bx % HF;

        for (int idx = tid; idx < C_CH * WF; idx += 256) {
            const int cc = idx / WF;
            const int w  = idx % WF;
            T[w*65 + cc] = feat[((size_t)(n*C_CH + cc)*HF + h)*WF + w];
        }
        __syncthreads();
        {
            const int cc = tid & 63, seg = tid >> 6;
            const int w0 = seg * 44;
            float run = 0.0f;
            #pragma unroll
            for (int i = 0; i < 44; ++i) {
                run += T[(w0 + i)*65 + cc];
                T[(w0 + i)*65 + cc] = run;
            }
            S[seg][cc] = run;
        }
        __syncthreads();
        {
            const int cc = tid & 63, seg = tid >> 6;
            float off = 0.0f;
            #pragma unroll
            for (int s = 0; s < 3; ++s)
                if (s < seg) off += S[s][cc];
            OFF[seg][cc] = off;
        }
        __syncthreads();
        float* outp = integ + (size_t)(n*HF + h) * (WF * C_CH);
        for (int idx = tid; idx < WF * C_CH; idx += 256) {
            const int w  = idx >> 6;
            const int cc = idx & 63;
            outp[idx] = T[w*65 + cc] + OFF[w/44][cc];
        }
        return;
    }

    // ---- boxproj: project 8 voxel corners + bbox -> packed params ----
    const int idx = (bx - HF*NCAM) * 256 + tid;
    if (idx >= NCAM * NH * NP) return;
    const int vox = idx / NCAM;
    const int n   = idx - vox * NCAM;     // cam fastest -> coalesced 32B writes
    const int nh  = vox / NP;
    const int p   = vox - nh * NP;
    const int d   = p / WDIM;
    const int wd  = p - d * WDIM;

    const float* k  = ks         + n * 9;
    const float* m  = imu2cs     + n * 12;
    const float* pr = post_rots  + n * 9;
    const float* pt = post_trans + n * 3;
    const float* D  = undists    + n * 7;

    float cal[12];
    #pragma unroll
    for (int i = 0; i < 3; ++i)
        #pragma unroll
        for (int j = 0; j < 4; ++j)
            cal[i*4+j] = k[i*3+0]*m[0*4+j] + k[i*3+1]*m[1*4+j] + k[i*3+2]*m[2*4+j];

    const float fx = k[0], fy = k[4], cx = k[2], cy = k[5];
    const float rfx = 1.0f / fx, rfy = 1.0f / fy;
    const bool fish = (D[6] == 1.0f);
    const float D0 = D[0], D1 = D[1], D2 = D[2], D3 = D[3], D4 = D[4], D5 = D[5];

    float left = 1e30f, right = -1e30f, top = 1e30f, bot = -1e30f;
    #pragma unroll
    for (int a = 0; a < 2; ++a) {
        const float vy = 2.0f - (float)(nh + a);   // ys = -arange(0,4)+2
        #pragma unroll
        for (int b = 0; b < 2; ++b) {
            #pragma unroll
            for (int cc = 0; cc < 2; ++cc) {
                const int gz = d + b, gx = wd + cc;
                const float vx = grid[(gz*GDIM + gx)*3 + 0];
                const float vz = grid[(gz*GDIM + gx)*3 + 2];

                const float hx = cal[0]*vx + cal[1]*vy + cal[2]*vz  + cal[3];
                const float hy = cal[4]*vx + cal[5]*vy + cal[6]*vz  + cal[7];
                const float hz = cal[8]*vx + cal[9]*vy + cal[10]*vz + cal[11];

                const float fl = (hz > 0.0f) ? 1.0f : 0.0f;
                const float px = (hx * fl) / hz;
                const float py = (hy * fl) / hz;

                const float x = (px - cx) * rfx;
                const float y = (py - cy) * rfy;

                float xd, yd;
                if (fish) {
                    const float rr = sqrtf(x*x + y*y);
                    const float th = atanf(rr);
                    const float t2 = th * th;
                    const float t4 = t2 * t2;
                    const float rad = th * (1.0f + D0*t2 + D1*t4 + D2*(t2*t4) + D5*(t4*t4)) / rr;
                    xd = x * rad * fx + cx;
                    yd = y * rad * fy + cy;
                } else {
                    const float r2 = x*x + y*y;
                    const float poly = 1.0f + D0*r2 + D1*r2*r2 + D2*r2*r2*r2;
                    const float xdd = x*poly + (2.0f*D3*x*y + D4*(r2 + 2.0f*x*x));
                    const float ydd = y*poly + (D3*(r2 + 2.0f*y*y) + 2.0f*D4*x*y);
                    xd = xdd * fx + cx;
                    yd = ydd * fy + cy;
                }
                xd *= fl; yd *= fl;

                const float qx = pr[0]*xd + pr[1]*yd + pt[0];
                const float qy = pr[3]*xd + pr[4]*yd + pt[1];
                const float ncx = fminf(fmaxf(2.0f*qx - 1.0f, -1.0f), 1.0f);
                const float ncy = fminf(fmaxf(2.0f*qy - 1.0f, -1.0f), 1.0f);

                left  = fminf(left,  ncx);  right = fmaxf(right, ncx);
                top   = fminf(top,   ncy);  bot   = fmaxf(bot,   ncy);
            }
        }
    }

    const float area = (right - left) * (bot - top) * (float)HF * (float)WF * 0.25f + 1e-6f;

    const float xLp = fminf(fmaxf((left  + 1.0f) * 0.5f * (float)(WF-1), 0.0f), (float)(WF-1));
    const float xRp = fminf(fmaxf((right + 1.0f) * 0.5f * (float)(WF-1), 0.0f), (float)(WF-1));
    const float yTp = fminf(fmaxf((top   + 1.0f) * 0.5f * (float)(HF-1), 0.0f), (float)(HF-1));
    const float yBp = fminf(fmaxf((bot   + 1.0f) * 0.5f * (float)(HF-1), 0.0f), (float)(HF-1));
    const float xL0 = floorf(xLp), xR0 = floorf(xRp), yT0 = floorf(yTp), yB0 = floorf(yBp);

    const int pyx = (int)yT0 | ((int)yB0 << 8) | ((int)xL0 << 16) | ((int)xR0 << 24);

    int4 o0, o1;
    o0.x = pyx;
    o0.y = __builtin_bit_cast(int, xLp - xL0);
    o0.z = __builtin_bit_cast(int, xRp - xR0);
    o0.w = __builtin_bit_cast(int, yTp - yT0);
    o1.x = __builtin_bit_cast(int, yBp - yB0);
    o1.y = __builtin_bit_cast(int, area);
    o1.z = 0; o1.w = 0;
    bp[(size_t)idx*2 + 0] = o0;
    bp[(size_t)idx*2 + 1] = o1;
}

// ---------------- Kernel 2: column cumsum IN PLACE -> integral [n][h][x][c] -----------
__global__ __launch_bounds__(256) void k_colcum(float* __restrict__ integ)
{
    __shared__ float tA[4][C_CH];
    const int x  = blockIdx.x;
    const int n  = blockIdx.y;
    const int c  = threadIdx.x & 63;
    const int hq = threadIdx.x >> 6;

    float* base = integ + (size_t)n*HF*WF*C_CH + (size_t)x * C_CH + c;
    float e[16];
    #pragma unroll
    for (int i = 0; i < 16; ++i)
        e[i] = base[(size_t)(hq*16 + i) * (WF*C_CH)];
    #pragma unroll
    for (int i = 1; i < 16; ++i)
        e[i] += e[i-1];
    tA[hq][c] = e[15];
    __syncthreads();
    float off = 0.0f;
    #pragma unroll
    for (int s = 0; s < 3; ++s)
        if (s < hq) off += tA[s][c];
    #pragma unroll
    for (int i = 0; i < 16; ++i)
        base[(size_t)(hq*16 + i) * (WF*C_CH)] = e[i] + off;
}

// ---------------- Kernel 3: sample integral image, combine, max over cameras ----------
// R7 geometry (1536 blocks XCD-banded, wave = 8 voxels, lane = channel) but cam-TRIPLE
// batching: 48 texel dword loads issued per batch (2 batches/voxel instead of 3) under
// __launch_bounds__(256,6) so the register allocator can keep all 48 destinations live
// -> 3x the per-wave memory-level parallelism of the VGPR-28 version. Params decoded
// to the scalar pipe via readlane; one-voxel-ahead vector prefetch of the param block.
__global__ __launch_bounds__(256, 6) void k_sample(const float* __restrict__ integ,
                                                   const int* __restrict__ bpi,
                                                   float* __restrict__ out)
{
    __shared__ float sm[32][65];
    const int bx   = blockIdx.x;
    const int xcd  = bx & 7;
    const int slot = bx >> 3;
    const int gt   = xcd * 192 + slot;          // contiguous tile band per XCD
    const int nh   = gt >> 9;
    const int p0   = (gt & 511) * 32;
    const int tid  = threadIdx.x;
    const int wave = __builtin_amdgcn_readfirstlane(tid >> 6);
    const int c    = tid & 63;
    const int pl   = (c < 48) ? c : (c - 48);    // dword index within 192B param block

    const int* bpw = bpi + (size_t)(nh*NP + p0 + wave*8) * 48;

    int vpc = bpw[pl];                            // params for j=0
    #pragma unroll 1
    for (int j = 0; j < 8; ++j) {
        int vpn = vpc;
        if (j < 7) vpn = bpw[(j + 1) * 48 + pl]; // prefetch next voxel's params

        float vmax = -3.402823466e38f;
        #pragma unroll
        for (int t3 = 0; t3 < 2; ++t3) {
            const int cA = t3*3, cB = t3*3 + 1, cC = t3*3 + 2;
            // decode all three cameras' params (SGPRs via readlane)
            const int fA = __builtin_amdgcn_readlane(vpc, cA*8 + 0);
            const float wxlA = bcf(__builtin_amdgcn_readlane(vpc, cA*8 + 1));
            const float wxrA = bcf(__builtin_amdgcn_readlane(vpc, cA*8 + 2));
            const float wytA = bcf(__builtin_amdgcn_readlane(vpc, cA*8 + 3));
            const float wybA = bcf(__builtin_amdgcn_readlane(vpc, cA*8 + 4));
            const float arA  = bcf(__builtin_amdgcn_readlane(vpc, cA*8 + 5));
            const int fB = __builtin_amdgcn_readlane(vpc, cB*8 + 0);
            const float wxlB = bcf(__builtin_amdgcn_readlane(vpc, cB*8 + 1));
            const float wxrB = bcf(__builtin_amdgcn_readlane(vpc, cB*8 + 2));
            const float wytB = bcf(__builtin_amdgcn_readlane(vpc, cB*8 + 3));
            const float wybB = bcf(__builtin_amdgcn_readlane(vpc, cB*8 + 4));
            const float arB  = bcf(__builtin_amdgcn_readlane(vpc, cB*8 + 5));
            const int fC = __builtin_amdgcn_readlane(vpc, cC*8 + 0);
            const float wxlC = bcf(__builtin_amdgcn_readlane(vpc, cC*8 + 1));
            const float wxrC = bcf(__builtin_amdgcn_readlane(vpc, cC*8 + 2));
            const float wytC = bcf(__builtin_amdgcn_readlane(vpc, cC*8 + 3));
            const float wybC = bcf(__builtin_amdgcn_readlane(vpc, cC*8 + 4));
            const float arC  = bcf(__builtin_amdgcn_readlane(vpc, cC*8 + 5));

            // issue ALL 48 texel loads before any compute
            float tA[16], tB[16], tC[16];
            {
                const int yT = fA & 255, yB2 = (fA >> 8) & 255;
                const int xL = (fA >> 16) & 255, xR = (fA >> 24) & 255;
                const int r0 = yT * ROWB, r2 = yB2 * ROWB;
                const int c0 = xL * COLB, c2 = xR * COLB;
                const char* b = (const char*)integ + (size_t)cA * IMGB;
                #pragma unroll
                for (int rr = 0; rr < 4; ++rr) {
                    const int ro = ((rr < 2) ? r0 : r2) + ((rr & 1) ? ROWB : 0);
                    #pragma unroll
                    for (int cc2 = 0; cc2 < 4; ++cc2) {
                        const int co = ((cc2 < 2) ? c0 : c2) + ((cc2 & 1) ? COLB : 0);
                        tA[rr*4 + cc2] = ((const float*)(b + (size_t)(ro + co)))[c];
                    }
                }
            }
            {
                const int yT = fB & 255, yB2 = (fB >> 8) & 255;
                const int xL = (fB >> 16) & 255, xR = (fB >> 24) & 255;
                const int r0 = yT * ROWB, r2 = yB2 * ROWB;
                const int c0 = xL * COLB, c2 = xR * COLB;
                const char* b = (const char*)integ + (size_t)cB * IMGB;
                #pragma unroll
                for (int rr = 0; rr < 4; ++rr) {
                    const int ro = ((rr < 2) ? r0 : r2) + ((rr & 1) ? ROWB : 0);
                    #pragma unroll
                    for (int cc2 = 0; cc2 < 4; ++cc2) {
                        const int co = ((cc2 < 2) ? c0 : c2) + ((cc2 & 1) ? COLB : 0);
                        tB[rr*4 + cc2] = ((const float*)(b + (size_t)(ro + co)))[c];
                    }
                }
            }
            {
                const int yT = fC & 255, yB2 = (fC >> 8) & 255;
                const int xL = (fC >> 16) & 255, xR = (fC >> 24) & 255;
                const int r0 = yT * ROWB, r2 = yB2 * ROWB;
                const int c0 = xL * COLB, c2 = xR * COLB;
                const char* b = (const char*)integ + (size_t)cC * IMGB;
                #pragma unroll
                for (int rr = 0; rr < 4; ++rr) {
                    const int ro = ((rr < 2) ? r0 : r2) + ((rr & 1) ? ROWB : 0);
                    #pragma unroll
                    for (int cc2 = 0; cc2 < 4; ++cc2) {
                        const int co = ((cc2 < 2) ? c0 : c2) + ((cc2 & 1) ? COLB : 0);
                        tC[rr*4 + cc2] = ((const float*)(b + (size_t)(ro + co)))[c];
                    }
                }
            }

            {
                const float A0 = fmaf(wxlA, tA[1]  - tA[0],  tA[0]);
                const float B0 = fmaf(wxrA, tA[3]  - tA[2],  tA[2]);
                const float A1 = fmaf(wxlA, tA[5]  - tA[4],  tA[4]);
                const float B1 = fmaf(wxrA, tA[7]  - tA[6],  tA[6]);
                const float A2 = fmaf(wxlA, tA[9]  - tA[8],  tA[8]);
                const float B2 = fmaf(wxrA, tA[11] - tA[10], tA[10]);
                const float A3 = fmaf(wxlA, tA[13] - tA[12], tA[12]);
                const float B3 = fmaf(wxrA, tA[15] - tA[14], tA[14]);
                const float d0 = A0 - B0, d1 = A1 - B1;
                const float e0 = B2 - A2, e1 = B3 - A3;
                const float s = fmaf(wytA, d1 - d0, d0) + fmaf(wybA, e1 - e0, e0);
                float v = s * __builtin_amdgcn_rcpf(arA);
                v = (arA > 1e-6f) ? v : 0.0f;    // reference: vox * (area > EPS)
                vmax = fmaxf(vmax, v);
            }
            {
                const float A0 = fmaf(wxlB, tB[1]  - tB[0],  tB[0]);
                const float B0 = fmaf(wxrB, tB[3]  - tB[2],  tB[2]);
                const float A1 = fmaf(wxlB, tB[5]  - tB[4],  tB[4]);
                const float B1 = fmaf(wxrB, tB[7]  - tB[6],  tB[6]);
                const float A2 = fmaf(wxlB, tB[9]  - tB[8],  tB[8]);
                const float B2 = fmaf(wxrB, tB[11] - tB[10], tB[10]);
                const float A3 = fmaf(wxlB, tB[13] - tB[12], tB[12]);
                const float B3 = fmaf(wxrB, tB[15] - tB[14], tB[14]);
                const float d0 = A0 - B0, d1 = A1 - B1;
                const float e0 = B2 - A2, e1 = B3 - A3;
                const float s = fmaf(wytB, d1 - d0, d0) + fmaf(wybB, e1 - e0, e0);
                float v = s * __builtin_amdgcn_rcpf(arB);
                v = (arB > 1e-6f) ? v : 0.0f;
                vmax = fmaxf(vmax, v);
            }
            {
                const float A0 = fmaf(wxlC, tC[1]  - tC[0],  tC[0]);
                const float B0 = fmaf(wxrC, tC[3]  - tC[2],  tC[2]);
                const float A1 = fmaf(wxlC, tC[5]  - tC[4],  tC[4]);
                const float B1 = fmaf(wxrC, tC[7]  - tC[6],  tC[6]);
                const float A2 = fmaf(wxlC, tC[9]  - tC[8],  tC[8]);
                const float B2 = fmaf(wxrC, tC[11] - tC[10], tC[10]);
                const float A3 = fmaf(wxlC, tC[13] - tC[12], tC[12]);
                const float B3 = fmaf(wxrC, tC[15] - tC[14], tC[14]);
                const float d0 = A0 - B0, d1 = A1 - B1;
                const float e0 = B2 - A2, e1 = B3 - A3;
                const float s = fmaf(wytC, d1 - d0, d0) + fmaf(wybC, e1 - e0, e0);
                float v = s * __builtin_amdgcn_rcpf(arC);
                v = (arC > 1e-6f) ? v : 0.0f;
                vmax = fmaxf(vmax, v);
            }
        }
        sm[wave*8 + j][c] = vmax;
        vpc = vpn;
    }
    __syncthreads();
    #pragma unroll
    for (int it = 0; it < 8; ++it) {
        const int idx = it*256 + tid;
        const int jj = idx & 31;
        const int cc = idx >> 5;
        out[(size_t)(cc*NH + nh)*NP + p0 + jj] = sm[jj][cc];
    }
}

extern "C" void kernel_launch(void* const* d_in, const int* in_sizes, int n_in,
                              void* d_out, int out_size, void* d_ws, size_t ws_size,
                              hipStream_t stream)
{
    const float* feats      = (const float*)d_in[0];  // [1,6,64,64,176]
    const float* ks         = (const float*)d_in[1];  // [1,6,3,3]
    const float* imu2cs     = (const float*)d_in[2];  // [1,6,3,4]
    const float* post_rots  = (const float*)d_in[3];  // [1,6,3,3]
    const float* post_trans = (const float*)d_in[4];  // [1,6,3]
    const float* undists    = (const float*)d_in[5];  // [1,6,7]
    const float* grid       = (const float*)d_in[6];  // [1,129,129,3]
    float* out = (float*)d_out;                       // [1,192,128,128]

    char* ws = (char*)d_ws;
    size_t off = 0;
    float* integ = (float*)(ws + off);                // rowsum then integral (in place)
    off += (size_t)NCAM * IMGB + ROWB + 65536;        // pad: clamp-free overreads (x0 wt)
    off = (off + 255) & ~(size_t)255;
    int4* bp = (int4*)(ws + off);
    off += (size_t)NCAM * NH * NP * 32 + 256;
    (void)ws_size; (void)in_sizes; (void)n_in; (void)out_size;

    // K1: fused row-cumsum (384 blocks) || boxproj (1152 blocks)
    dim3 g1(HF*NCAM + (NCAM*NH*NP + 255)/256);
    k_prep<<<g1, 256, 0, stream>>>(feats, integ, ks, imu2cs, post_rots, post_trans,
                                   undists, grid, bp);

    // K2: column cumsum in place
    dim3 g2(WF, NCAM);
    k_colcum<<<g2, 256, 0, stream>>>(integ);

    // K3: sampling, 1536 blocks (6/CU), cam-triple MLP
    dim3 g3(NP/32 * NH);
    k_sample<<<g3, 256, 0, stream>>>(integ, (const int*)bp, out);
}